// Round 1
// baseline (303.715 us; speedup 1.0000x reference)
//
#include <hip/hip_runtime.h>
#include <math.h>

#define TT 1024
#define NN 64
#define CC 128
#define SS 128
#define SX 257            // 2*S+1
#define NC (NN * CC)      // stride between time steps in log_probs

// One block per batch element n. 320 threads = 5 waves:
//  - threads 0..127 stage the emission row log_probs[t, n, :] (512 B)
//  - threads 0..256 each own one extended state s
// alpha double-buffered in LDS; emission rows prefetched 4 steps ahead
// into registers (async-STAGE split) to hide HBM latency under compute.
__global__ __launch_bounds__(320) void ctc_alpha(
    const float* __restrict__ lp,        // [T, N, C] fp32
    const int*   __restrict__ targets,   // [N, S]
    const int*   __restrict__ ilen,      // [N]
    const int*   __restrict__ tlen,      // [N]
    float*       __restrict__ v_out)     // [N] terminal alpha values
{
    const int n   = blockIdx.x;
    const int tid = threadIdx.x;

    __shared__ float alpha[2][SX];
    __shared__ float emitb[2][CC];
    __shared__ int   lab[SX];
    __shared__ unsigned char skipf[SX];

    const float* lp_n = lp + (size_t)n * CC;

    // issue prefetches for rows 0..4 as early as possible
    float r0 = 0.f, ra = 0.f, rb = 0.f, rc = 0.f, rd = 0.f;
    if (tid < CC) {
        r0 = lp_n[tid];
        ra = lp_n[(size_t)1 * NC + tid];
        rb = lp_n[(size_t)2 * NC + tid];
        rc = lp_n[(size_t)3 * NC + tid];
        rd = lp_n[(size_t)4 * NC + tid];
    }

    // extended label sequence: blanks (0) at even s, targets at odd s
    if (tid < SX) {
        lab[tid] = (tid & 1) ? targets[n * SS + (tid >> 1)] : 0;
    }
    __syncthreads();
    if (tid < SX) {
        skipf[tid] = (tid >= 2) && (lab[tid] != lab[tid - 2]);
    }
    if (tid < CC) emitb[0][tid] = r0;

    const int il = ilen[n];
    const int vs = 2 * tlen[n] - 1;
    __syncthreads();

    // t = 0 init — faithful to reference: alpha0 is ZEROS except s=0,1
    int ca = 0;
    if (tid < SX) {
        float a;
        if (tid == 0)      a = emitb[0][0];
        else if (tid == 1) a = emitb[0][lab[1]];
        else               a = 0.f;
        alpha[0][tid] = a;
        if (il == 1 && tid == vs) v_out[n] = a;
    }

    const float NEGINF = -INFINITY;

    auto step = [&](int t, float& rhold) {
        __syncthreads();  // WAR: emitb[t&1] (read at t-2) and alpha[ca^1] (read at t-1)
        if (tid < CC) {
            emitb[t & 1][tid] = rhold;                       // waits only this reg
            if (t + 4 < TT)
                rhold = lp_n[(size_t)(t + 4) * NC + tid];    // prefetch 4 ahead
        }
        __syncthreads();  // emit row + previous alpha visible
        if (tid < SX) {
            float a0 = alpha[ca][tid];
            float a1 = (tid >= 1) ? alpha[ca][tid - 1] : NEGINF;
            float a2 = skipf[tid] ? alpha[ca][tid - 2] : NEGINF;
            float e  = emitb[t & 1][lab[tid]];
            float m  = fmaxf(a0, fmaxf(a1, a2));
            // m is one of {a0,a1,a2} and a0 is always finite -> m finite
            float nv = m + __logf(__expf(a0 - m) + __expf(a1 - m) + __expf(a2 - m)) + e;
            alpha[ca ^ 1][tid] = nv;
            if (t == il - 1 && tid == vs) v_out[n] = nv;
        }
        ca ^= 1;
    };

    // t = 1 .. 1020 in groups of 4 (named regs keep prefetch slots static)
    for (int t = 1; t + 3 < TT; t += 4) {
        step(t,     ra);
        step(t + 1, rb);
        step(t + 2, rc);
        step(t + 3, rd);
    }
    // leftover t = 1021, 1022, 1023
    step(1021, ra);
    step(1022, rb);
    step(1023, rc);
}

// loss = -logsumexp(v) over the 64 batch elements; single wave
__global__ void ctc_reduce(const float* __restrict__ v, float* __restrict__ out)
{
    const int lane = threadIdx.x;  // 64 threads
    float x = v[lane];
    float m = x;
#pragma unroll
    for (int off = 32; off > 0; off >>= 1) m = fmaxf(m, __shfl_xor(m, off));
    float e = __expf(x - m);
#pragma unroll
    for (int off = 32; off > 0; off >>= 1) e += __shfl_xor(e, off);
    if (lane == 0) out[0] = -(m + __logf(e));
}

extern "C" void kernel_launch(void* const* d_in, const int* in_sizes, int n_in,
                              void* d_out, int out_size, void* d_ws, size_t ws_size,
                              hipStream_t stream) {
    const float* lp      = (const float*)d_in[0];
    const int*   targets = (const int*)d_in[1];
    const int*   ilen    = (const int*)d_in[2];
    const int*   tlen    = (const int*)d_in[3];

    float* v   = (float*)d_ws;   // 64 floats of scratch
    float* out = (float*)d_out;  // scalar fp32 loss

    ctc_alpha<<<NN, 320, 0, stream>>>(lp, targets, ilen, tlen, v);
    ctc_reduce<<<1, 64, 0, stream>>>(v, out);
}

// Round 2
// 135.648 us; speedup vs baseline: 2.2390x; 2.2390x over previous
//
#include <hip/hip_runtime.h>
#include <math.h>

#define TT 1024
#define NN 64
#define CC 128
#define SS 128
#define NC (NN * CC)   // stride between time rows

// One WAVE (64 threads) per batch element. No __syncthreads anywhere.
// Lane l owns extended states s = 4l .. 4l+3 in registers:
//   s=4l   (blank): new0 = (a0 + a3_prev) * pb
//   s=4l+1 (tgA):   new1 = (a0 + a1 + k1*a3_prev) * pa    k1 = (tgA != prev lane tgB)
//   s=4l+2 (blank): new2 = (a1 + a2) * pb
//   s=4l+3 (tgB):   new3 = (a2 + a3 + k3*a1) * pc         k3 = (tgB != tgA)
// Only ONE cross-lane value per step (prev lane's a3) -> single ds_bpermute,
// issued immediately after new3, consumed next step (latency hidden).
// Linear domain with wave-uniform renorm every 8 steps (pipelined shfl_xor
// max, applied 7 steps stale -- values only shrink, so stale is safe);
// running per-lane (uniform) log-scale ls keeps true_alpha = a * e^ls.
// State 256 is dropped: it feeds no other state and the terminal index
// 2*tlen-1 <= 255 is always odd.
__global__ __launch_bounds__(64) void ctc_alpha(
    const float* __restrict__ lp,        // [T, N, C] fp32 (log-softmax)
    const int*   __restrict__ targets,   // [N, S]
    const int*   __restrict__ ilen,      // [N]
    const int*   __restrict__ tlen,      // [N]
    float*       __restrict__ v_out)     // [N] terminal log-alpha
{
    const int n    = blockIdx.x;
    const int lane = threadIdx.x;
    const float* lp_n = lp + (size_t)n * CC;

    const int tgA  = targets[n * SS + 2 * lane];
    const int tgB  = targets[n * SS + 2 * lane + 1];
    const int tgBm = (lane > 0) ? targets[n * SS + 2 * lane - 1] : -1;
    const float k1f = (lane > 0 && tgA != tgBm) ? 1.f : 0.f;
    const float k3f = (tgB != tgA) ? 1.f : 0.f;

    const int il    = ilen[n];
    const int vs    = 2 * tlen[n] - 1;   // odd, in [127, 255]
    const int vlane = vs >> 2;

    // t = 0 init, faithful to reference (zeros init == prob 1 in linear domain)
    float a0 = (lane == 0) ? __expf(lp_n[0])    : 1.f;
    float a1 = (lane == 0) ? __expf(lp_n[tgA])  : 1.f;
    float a2 = 1.f, a3 = 1.f;
    float a3p = (lane == 0) ? 0.f : 1.f;   // prev-lane a3 for step t=1
    float ls  = 0.f;

    // emission pipeline: pex (exp'd, rows t..t+7) and raw in-flight (rows t+8..t+15)
    float pb[8], pa[8], pc[8], rb[8], ra[8], rc[8];
#pragma unroll
    for (int j = 0; j < 8; ++j) {
        const float* row = lp_n + (size_t)(1 + j) * NC;
        pb[j] = row[0]; pa[j] = row[tgA]; pc[j] = row[tgB];
    }
#pragma unroll
    for (int j = 0; j < 8; ++j) {
        pb[j] = __expf(pb[j]); pa[j] = __expf(pa[j]); pc[j] = __expf(pc[j]);
        const float* row = lp_n + (size_t)(9 + j) * NC;
        rb[j] = row[0]; ra[j] = row[tgA]; rc[j] = row[tgB];
    }

    const int bpaddr = ((lane == 0) ? 0 : (lane - 1)) << 2;  // bpermute byte addr

    float mr = 1.f, hop = 1.f, inv = 1.f, lm = 0.f;

    for (int g = 0; g < 128; ++g) {
        const int tbase = 1 + g * 8;
#pragma unroll
        for (int j = 0; j < 8; ++j) {
            const int t = tbase + j;

            // new3 first, so its shuffle is issued as early as possible
            float nb3 = fmaf(k3f, a1, a3 + a2) * pc[j];
            int nxt_i = __builtin_amdgcn_ds_bpermute(bpaddr, __float_as_int(nb3));
            float nb0 = (a0 + a3p) * pb[j];
            float nb1 = fmaf(k1f, a3p, a0 + a1) * pa[j];
            float nb2 = (a2 + a1) * pb[j];

            // pipelined wave-max renorm: hop issued at j, combined at j+1
            if (j == 0)      { mr = fmaxf(fmaxf(nb0, nb1), fmaxf(nb2, nb3)); hop = __shfl_xor(mr, 1); }
            else if (j <= 5) { mr = fmaxf(mr, hop); hop = __shfl_xor(mr, 1 << j); }
            else if (j == 6) { mr = fmaxf(mr, hop); }  // mr final (wave-uniform)
            else { // j == 7: apply renorm (7 steps stale -- safe, values shrink)
                inv = 1.0f / mr;
                lm  = __logf(mr);
                nb0 *= inv; nb1 *= inv; nb2 *= inv; nb3 *= inv;
                ls += lm;
            }

            // terminal capture (il uniform per block; branch almost never taken)
            if (t == il - 1) {
                if (lane == vlane) {
                    float val = (vs & 2) ? nb3 : nb1;
                    v_out[n] = __logf(val) + ls;
                }
            }

            a0 = nb0; a1 = nb1; a2 = nb2; a3 = nb3;
            float a3pn = (lane == 0) ? 0.f : __int_as_float(nxt_i);
            if (j == 7) a3pn *= inv;   // keep consistent with the rescale
            a3p = a3pn;

            // rotate emission pipeline: exp arrived raw, issue load 16 steps ahead
            pb[j] = __expf(rb[j]); pa[j] = __expf(ra[j]); pc[j] = __expf(rc[j]);
            int tf = t + 16; tf = (tf > TT - 1) ? (TT - 1) : tf;  // clamp (unused tail)
            const float* row = lp_n + (size_t)tf * NC;
            rb[j] = row[0]; ra[j] = row[tgA]; rc[j] = row[tgB];
        }
    }
    // loop runs t = 1..1024; step 1024 computes garbage from a clamped row but
    // is never captured (il-1 <= 1023). All real steps use correct rows.
}

// loss = -logsumexp(v) over the 64 batch elements; single wave
__global__ void ctc_reduce(const float* __restrict__ v, float* __restrict__ out)
{
    const int lane = threadIdx.x;  // 64 threads
    float x = v[lane];
    float m = x;
#pragma unroll
    for (int off = 32; off > 0; off >>= 1) m = fmaxf(m, __shfl_xor(m, off));
    float e = __expf(x - m);
#pragma unroll
    for (int off = 32; off > 0; off >>= 1) e += __shfl_xor(e, off);
    if (lane == 0) out[0] = -(m + __logf(e));
}

extern "C" void kernel_launch(void* const* d_in, const int* in_sizes, int n_in,
                              void* d_out, int out_size, void* d_ws, size_t ws_size,
                              hipStream_t stream) {
    const float* lp      = (const float*)d_in[0];
    const int*   targets = (const int*)d_in[1];
    const int*   ilen    = (const int*)d_in[2];
    const int*   tlen    = (const int*)d_in[3];

    float* v   = (float*)d_ws;   // 64 floats of scratch
    float* out = (float*)d_out;  // scalar fp32 loss

    ctc_alpha<<<NN, 64, 0, stream>>>(lp, targets, ilen, tlen, v);
    ctc_reduce<<<1, 64, 0, stream>>>(v, out);
}

// Round 3
// 113.651 us; speedup vs baseline: 2.6724x; 1.1936x over previous
//
#include <hip/hip_runtime.h>
#include <math.h>

#define TT 1024
#define NN 64
#define CC 128
#define SS 128
#define NC (NN * CC)   // stride between time rows (floats)

// ---------------------------------------------------------------------------
// Kernel A (parallel): gather + exp the 3 emission probs each scan-lane needs.
// E[(t*NN+n)*64 + lane] = { exp(lp[t,n,0]), exp(lp[t,n,tgA]), exp(lp[t,n,tgB]), 0 }
// One wave per (n,t) pair; 4 waves/block share the same n (targets row in L1).
__global__ __launch_bounds__(256) void ctc_emit(
    const float* __restrict__ lp,
    const int*   __restrict__ targets,
    float4*      __restrict__ E)
{
    const int wid  = blockIdx.x * 4 + (threadIdx.x >> 6);
    const int lane = threadIdx.x & 63;
    const int t = wid & (TT - 1);
    const int n = wid >> 10;

    const float* row = lp + ((size_t)t * NN + n) * CC;
    const int tgA = targets[n * SS + 2 * lane];
    const int tgB = targets[n * SS + 2 * lane + 1];

    const float pb = __expf(row[0]);      // broadcast load
    const float pa = __expf(row[tgA]);
    const float pc = __expf(row[tgB]);
    E[(size_t)(t * NN + n) * 64 + lane] = make_float4(pb, pa, pc, 0.f);
}

// ---------------------------------------------------------------------------
// Kernel B (serial): one wave per batch element, alpha in registers,
// one coalesced float4 load per step, 16-deep static rotating prefetch.
// Math identical to the (verified) round-2 kernel.
__global__ __launch_bounds__(64) void ctc_scan(
    const float4* __restrict__ E,
    const int*    __restrict__ targets,
    const int*    __restrict__ ilen,
    const int*    __restrict__ tlen,
    float*        __restrict__ v_out)
{
    const int n    = blockIdx.x;
    const int lane = threadIdx.x;

    const int tgA  = targets[n * SS + 2 * lane];
    const int tgB  = targets[n * SS + 2 * lane + 1];
    const int tgBm = (lane > 0) ? targets[n * SS + 2 * lane - 1] : -1;
    const float k1f = (lane > 0 && tgA != tgBm) ? 1.f : 0.f;
    const float k3f = (tgB != tgA) ? 1.f : 0.f;

    const int il    = ilen[n];
    const int vs    = 2 * tlen[n] - 1;   // odd, in [127, 255]
    const int vlane = vs >> 2;

    const float4* En = E + (size_t)n * 64 + lane;   // step stride = NN*64 float4s

    // t = 0 init (reference: alpha0 zeros except s=0,1; zeros == prob 1 linear)
    const float4 e0 = En[0];
    float a0  = (lane == 0) ? e0.x : 1.f;
    float a1  = (lane == 0) ? e0.y : 1.f;
    float a2  = 1.f, a3 = 1.f;
    float a3p = (lane == 0) ? 0.f : 1.f;
    float ls  = 0.f;

    float4 pipe[16];
#pragma unroll
    for (int j = 0; j < 16; ++j) pipe[j] = En[(size_t)(1 + j) * (NN * 64)];

    const int bpaddr = ((lane == 0) ? 0 : (lane - 1)) << 2;
    float mr = 1.f, hop = 1.f, inv = 1.f;

    for (int g = 0; g < 64; ++g) {
        const int tbase = 1 + g * 16;
#pragma unroll
        for (int j = 0; j < 16; ++j) {
            const int t = tbase + j;

            const float4 cur = pipe[j];
            int tf = t + 16; tf = (tf > TT - 1) ? (TT - 1) : tf;
            pipe[j] = En[(size_t)tf * (NN * 64)];   // refill 16 steps ahead

            // new3 first so its cross-lane shuffle issues early
            float nb3 = fmaf(k3f, a1, a3 + a2) * cur.z;
            const int nxt_i = __builtin_amdgcn_ds_bpermute(bpaddr, __float_as_int(nb3));
            float nb0 = (a0 + a3p) * cur.x;
            float nb1 = fmaf(k1f, a3p, a0 + a1) * cur.y;
            float nb2 = (a2 + a1) * cur.x;

            // pipelined wave-max renorm, applied every 8 steps (stale-safe)
            const int jj = j & 7;
            if (jj == 0)      { mr = fmaxf(fmaxf(nb0, nb1), fmaxf(nb2, nb3)); hop = __shfl_xor(mr, 1); }
            else if (jj <= 5) { mr = fmaxf(mr, hop); hop = __shfl_xor(mr, 1 << jj); }
            else if (jj == 6) { mr = fmaxf(mr, hop); }
            else { inv = 1.0f / mr; ls += __logf(mr); nb0 *= inv; nb1 *= inv; nb2 *= inv; nb3 *= inv; }

            if (t == il - 1) {
                if (lane == vlane) v_out[n] = __logf((vs & 2) ? nb3 : nb1) + ls;
            }

            a0 = nb0; a1 = nb1; a2 = nb2; a3 = nb3;
            float a3pn = (lane == 0) ? 0.f : __int_as_float(nxt_i);
            if (jj == 7) a3pn *= inv;
            a3p = a3pn;
        }
    }
    // covers t = 1..1024; step 1024 is garbage from a clamped row, never captured.
}

// ---------------------------------------------------------------------------
// Fallback (verified round-2 kernel) for the case ws_size < 64 MiB.
__global__ __launch_bounds__(64) void ctc_alpha_fb(
    const float* __restrict__ lp,
    const int*   __restrict__ targets,
    const int*   __restrict__ ilen,
    const int*   __restrict__ tlen,
    float*       __restrict__ v_out)
{
    const int n    = blockIdx.x;
    const int lane = threadIdx.x;
    const float* lp_n = lp + (size_t)n * CC;

    const int tgA  = targets[n * SS + 2 * lane];
    const int tgB  = targets[n * SS + 2 * lane + 1];
    const int tgBm = (lane > 0) ? targets[n * SS + 2 * lane - 1] : -1;
    const float k1f = (lane > 0 && tgA != tgBm) ? 1.f : 0.f;
    const float k3f = (tgB != tgA) ? 1.f : 0.f;

    const int il    = ilen[n];
    const int vs    = 2 * tlen[n] - 1;
    const int vlane = vs >> 2;

    float a0 = (lane == 0) ? __expf(lp_n[0])   : 1.f;
    float a1 = (lane == 0) ? __expf(lp_n[tgA]) : 1.f;
    float a2 = 1.f, a3 = 1.f;
    float a3p = (lane == 0) ? 0.f : 1.f;
    float ls  = 0.f;

    float pb[8], pa[8], pc[8], rb[8], ra[8], rc[8];
#pragma unroll
    for (int j = 0; j < 8; ++j) {
        const float* row = lp_n + (size_t)(1 + j) * NC;
        pb[j] = row[0]; pa[j] = row[tgA]; pc[j] = row[tgB];
    }
#pragma unroll
    for (int j = 0; j < 8; ++j) {
        pb[j] = __expf(pb[j]); pa[j] = __expf(pa[j]); pc[j] = __expf(pc[j]);
        const float* row = lp_n + (size_t)(9 + j) * NC;
        rb[j] = row[0]; ra[j] = row[tgA]; rc[j] = row[tgB];
    }

    const int bpaddr = ((lane == 0) ? 0 : (lane - 1)) << 2;
    float mr = 1.f, hop = 1.f, inv = 1.f;

    for (int g = 0; g < 128; ++g) {
        const int tbase = 1 + g * 8;
#pragma unroll
        for (int j = 0; j < 8; ++j) {
            const int t = tbase + j;
            float nb3 = fmaf(k3f, a1, a3 + a2) * pc[j];
            int nxt_i = __builtin_amdgcn_ds_bpermute(bpaddr, __float_as_int(nb3));
            float nb0 = (a0 + a3p) * pb[j];
            float nb1 = fmaf(k1f, a3p, a0 + a1) * pa[j];
            float nb2 = (a2 + a1) * pb[j];

            if (j == 0)      { mr = fmaxf(fmaxf(nb0, nb1), fmaxf(nb2, nb3)); hop = __shfl_xor(mr, 1); }
            else if (j <= 5) { mr = fmaxf(mr, hop); hop = __shfl_xor(mr, 1 << j); }
            else if (j == 6) { mr = fmaxf(mr, hop); }
            else { inv = 1.0f / mr; ls += __logf(mr); nb0 *= inv; nb1 *= inv; nb2 *= inv; nb3 *= inv; }

            if (t == il - 1) {
                if (lane == vlane) v_out[n] = __logf((vs & 2) ? nb3 : nb1) + ls;
            }

            a0 = nb0; a1 = nb1; a2 = nb2; a3 = nb3;
            float a3pn = (lane == 0) ? 0.f : __int_as_float(nxt_i);
            if (j == 7) a3pn *= inv;
            a3p = a3pn;

            pb[j] = __expf(rb[j]); pa[j] = __expf(ra[j]); pc[j] = __expf(rc[j]);
            int tf = t + 16; tf = (tf > TT - 1) ? (TT - 1) : tf;
            const float* row = lp_n + (size_t)tf * NC;
            rb[j] = row[0]; ra[j] = row[tgA]; rc[j] = row[tgB];
        }
    }
}

// loss = -logsumexp(v) over the 64 batch elements; single wave
__global__ void ctc_reduce(const float* __restrict__ v, float* __restrict__ out)
{
    const int lane = threadIdx.x;
    float x = v[lane];
    float m = x;
#pragma unroll
    for (int off = 32; off > 0; off >>= 1) m = fmaxf(m, __shfl_xor(m, off));
    float e = __expf(x - m);
#pragma unroll
    for (int off = 32; off > 0; off >>= 1) e += __shfl_xor(e, off);
    if (lane == 0) out[0] = -(m + __logf(e));
}

extern "C" void kernel_launch(void* const* d_in, const int* in_sizes, int n_in,
                              void* d_out, int out_size, void* d_ws, size_t ws_size,
                              hipStream_t stream) {
    const float* lp      = (const float*)d_in[0];
    const int*   targets = (const int*)d_in[1];
    const int*   ilen    = (const int*)d_in[2];
    const int*   tlen    = (const int*)d_in[3];

    float* v   = (float*)d_ws;    // 64 floats
    float* out = (float*)d_out;

    const size_t NEED = 256 + (size_t)TT * NN * 64 * sizeof(float4);  // 64 MiB + 256 B
    if (ws_size >= NEED) {
        float4* E = (float4*)((char*)d_ws + 256);
        ctc_emit<<<TT * NN / 4, 256, 0, stream>>>(lp, targets, E);
        ctc_scan<<<NN, 64, 0, stream>>>(E, targets, ilen, tlen, v);
    } else {
        ctc_alpha_fb<<<NN, 64, 0, stream>>>(lp, targets, ilen, tlen, v);
    }
    ctc_reduce<<<1, 64, 0, stream>>>(v, out);
}

// Round 4
// 90.213 us; speedup vs baseline: 3.3666x; 1.2598x over previous
//
#include <hip/hip_runtime.h>
#include <math.h>

#define TT 1024
#define NN 64
#define CC 128
#define SS 128
#define CH 32          // steps per chunk
#define NCHUNK 32      // chunks covering t = 1..1024

// Fused producer/consumer CTC forward scan. One block per batch element n.
// 3 waves: wave 0 = consumer (serial recurrence, alpha in registers),
// waves 1,2 = producers (gather + exp emissions for the NEXT 32-step chunk
// into a double-buffered LDS ring). One __syncthreads per chunk.
//
// Lane l of the consumer owns extended states s = 4l .. 4l+3:
//   nb0 = (a0 + a3p) * pb                      (blank)
//   nb1 = (a0 + a1 + k1*a3p) * pa              (tgA)   k1 = tgA != prev-lane tgB
//   nb2 = (a2 + a1) * pb                       (blank)
//   nb3 = (a3 + a2 + k3*a1) * pc               (tgB)   k3 = tgB != tgA
// a3p = prev lane's a3 via ds_bpermute (issued at step t, consumed t+1).
// Linear domain, wave-uniform renorm every 8 steps (pipelined shfl_xor max,
// applied 7 steps stale -- safe, values only shrink). Math identical to the
// verified round-2/3 kernels (absmax 0).
__global__ __launch_bounds__(192) void ctc_scan(
    const float* __restrict__ lp,        // [T, N, C] fp32 log-softmax
    const int*   __restrict__ targets,   // [N, S]
    const int*   __restrict__ ilen,      // [N]
    const int*   __restrict__ tlen,      // [N]
    float*       __restrict__ v_out)     // [N] terminal log-alpha
{
    const int n    = blockIdx.x;
    const int tid  = threadIdx.x;
    const int wv   = tid >> 6;           // 0 = consumer, 1/2 = producers
    const int lane = tid & 63;

    __shared__ float s_pa[2][CH][64];    // exp(lp[t,n,tgA[lane]])
    __shared__ float s_pc[2][CH][64];    // exp(lp[t,n,tgB[lane]])
    __shared__ float s_pb[2][CH];        // exp(lp[t,n,0])

    const int tgA = targets[n * SS + 2 * lane];
    const int tgB = targets[n * SS + 2 * lane + 1];
    const float* lpn = lp + (size_t)n * CC;      // row t at lpn + t*NN*CC

    // ---------------- prologue: producers fill chunk 0 (t = 1..32) ----------
    if (wv != 0) {
        const int w = wv - 1;            // handles steps j = w, w+2, ..., w+30
        float va[16], vc[16];
#pragma unroll
        for (int i = 0; i < 16; ++i) {
            const int j = 2 * i + w;
            const float* row = lpn + (size_t)(1 + j) * (NN * CC);
            va[i] = row[tgA]; vc[i] = row[tgB];
        }
        float pbv = 0.f;
        if (w == 0 && lane < CH) pbv = lpn[(size_t)(1 + lane) * (NN * CC)];
#pragma unroll
        for (int i = 0; i < 16; ++i) {
            const int j = 2 * i + w;
            s_pa[0][j][lane] = __expf(va[i]);
            s_pc[0][j][lane] = __expf(vc[i]);
        }
        if (w == 0 && lane < CH) s_pb[0][lane] = __expf(pbv);
    }

    // consumer-side constants + t=0 init (reference: alpha0 zeros except s=0,1;
    // zeros in log domain == 1.0 in linear domain)
    const int tgBm = (lane > 0) ? targets[n * SS + 2 * lane - 1] : -1;
    const float k1f = (lane > 0 && tgA != tgBm) ? 1.f : 0.f;
    const float k3f = (tgB != tgA) ? 1.f : 0.f;
    const int il    = ilen[n];
    const int vs    = 2 * tlen[n] - 1;   // odd, in [127, 255]
    const int vlane = vs >> 2;

    float a0 = 1.f, a1 = 1.f, a2 = 1.f, a3 = 1.f, ls = 0.f;
    if (wv == 0) {
        a0 = (lane == 0) ? __expf(lpn[0])   : 1.f;
        a1 = (lane == 0) ? __expf(lpn[tgA]) : 1.f;
    }
    float a3p = (lane == 0) ? 0.f : 1.f;

    const int bpaddr = ((lane == 0) ? 0 : (lane - 1)) << 2;
    float mr = 1.f, hop = 1.f, inv = 1.f;

    __syncthreads();

    // ---------------- main loop: 32 chunks of 32 steps ----------------------
    for (int cc = 0; cc < NCHUNK; ++cc) {
        const int b = cc & 1;
        if (wv == 0) {
            const int t0 = 1 + cc * CH;
            // 2-step named-reg LDS prefetch
            float qa0 = s_pa[b][0][lane], qc0 = s_pc[b][0][lane], qb0 = s_pb[b][0];
            float qa1 = s_pa[b][1][lane], qc1 = s_pc[b][1][lane], qb1 = s_pb[b][1];
#pragma unroll
            for (int j = 0; j < CH; ++j) {
                const float cpa = qa0, cpc = qc0, cpb = qb0;
                qa0 = qa1; qc0 = qc1; qb0 = qb1;
                if (j + 2 < CH) {
                    qa1 = s_pa[b][j + 2][lane];
                    qc1 = s_pc[b][j + 2][lane];
                    qb1 = s_pb[b][j + 2];
                }

                // nb3 first so its cross-lane bpermute issues early
                float nb3 = fmaf(k3f, a1, a3 + a2) * cpc;
                const int nxt_i = __builtin_amdgcn_ds_bpermute(bpaddr, __float_as_int(nb3));
                float nb0 = (a0 + a3p) * cpb;
                float nb1 = fmaf(k1f, a3p, a0 + a1) * cpa;
                float nb2 = (a2 + a1) * cpb;

                // pipelined wave-max renorm, applied every 8 steps (stale-safe)
                const int jj = j & 7;
                if (jj == 0)      { mr = fmaxf(fmaxf(nb0, nb1), fmaxf(nb2, nb3)); hop = __shfl_xor(mr, 1); }
                else if (jj <= 5) { mr = fmaxf(mr, hop); hop = __shfl_xor(mr, 1 << jj); }
                else if (jj == 6) { mr = fmaxf(mr, hop); }
                else { inv = 1.0f / mr; ls += __logf(mr); nb0 *= inv; nb1 *= inv; nb2 *= inv; nb3 *= inv; }

                const int t = t0 + j;
                if (t == il - 1) {
                    if (lane == vlane) v_out[n] = __logf((vs & 2) ? nb3 : nb1) + ls;
                }

                a0 = nb0; a1 = nb1; a2 = nb2; a3 = nb3;
                float a3pn = (lane == 0) ? 0.f : __int_as_float(nxt_i);
                if (jj == 7) a3pn *= inv;
                a3p = a3pn;
            }
            // t = 1024 (last step of last chunk) computes garbage from a
            // clamped row but is never captured (il-1 <= 1023).
        } else if (cc + 1 < NCHUNK) {
            // producers fill chunk cc+1 into the other buffer
            const int w  = wv - 1;
            const int b2 = (cc + 1) & 1;
            const int t0 = 1 + (cc + 1) * CH;
            float va[16], vc[16];
#pragma unroll
            for (int i = 0; i < 16; ++i) {
                const int j = 2 * i + w;
                int t = t0 + j; if (t > TT - 1) t = TT - 1;   // clamp (t=1024 tail)
                const float* row = lpn + (size_t)t * (NN * CC);
                va[i] = row[tgA]; vc[i] = row[tgB];
            }
            float pbv = 0.f;
            if (w == 0 && lane < CH) {
                int t = t0 + lane; if (t > TT - 1) t = TT - 1;
                pbv = lpn[(size_t)t * (NN * CC)];
            }
#pragma unroll
            for (int i = 0; i < 16; ++i) {
                const int j = 2 * i + w;
                s_pa[b2][j][lane] = __expf(va[i]);
                s_pc[b2][j][lane] = __expf(vc[i]);
            }
            if (w == 0 && lane < CH) s_pb[b2][lane] = __expf(pbv);
        }
        __syncthreads();
    }
}

// loss = -logsumexp(v) over the 64 batch elements; single wave
__global__ void ctc_reduce(const float* __restrict__ v, float* __restrict__ out)
{
    const int lane = threadIdx.x;
    float x = v[lane];
    float m = x;
#pragma unroll
    for (int off = 32; off > 0; off >>= 1) m = fmaxf(m, __shfl_xor(m, off));
    float e = __expf(x - m);
#pragma unroll
    for (int off = 32; off > 0; off >>= 1) e += __shfl_xor(e, off);
    if (lane == 0) out[0] = -(m + __logf(e));
}

extern "C" void kernel_launch(void* const* d_in, const int* in_sizes, int n_in,
                              void* d_out, int out_size, void* d_ws, size_t ws_size,
                              hipStream_t stream) {
    const float* lp      = (const float*)d_in[0];
    const int*   targets = (const int*)d_in[1];
    const int*   ilen    = (const int*)d_in[2];
    const int*   tlen    = (const int*)d_in[3];

    float* v   = (float*)d_ws;    // 64 floats of scratch
    float* out = (float*)d_out;

    ctc_scan<<<NN, 192, 0, stream>>>(lp, targets, ilen, tlen, v);
    ctc_reduce<<<1, 64, 0, stream>>>(v, out);
}

// Round 5
// 85.123 us; speedup vs baseline: 3.5679x; 1.0598x over previous
//
#include <hip/hip_runtime.h>
#include <math.h>

#define TT 1024
#define NN 64
#define CC 128
#define SS 128
#define CH 32          // steps per chunk
#define NCHUNK 32      // chunks covering t = 1..1024

// DPP controls (gfx9/CDNA encodings; removed on RDNA, present on CDNA4)
#define DPP_QP_XOR1   0xB1   // quad_perm [1,0,3,2]
#define DPP_QP_XOR2   0x4E   // quad_perm [2,3,0,1]
#define DPP_WAVE_SHR1 0x138  // whole-wave shift right by 1 lane
#define DPP_ROW_MIRR  0x140  // mirror within 16 (xor 15)
#define DPP_HALF_MIRR 0x141  // mirror within 8  (xor 7)
#define DPP_BCAST15   0x142  // lane15 -> next row
#define DPP_BCAST31   0x143  // lane31 -> upper half

template <int CTRL>
__device__ __forceinline__ float dpp_max_stage(float v) {
    int p = __builtin_amdgcn_update_dpp(__float_as_int(v), __float_as_int(v),
                                        CTRL, 0xF, 0xF, false);
    return fmaxf(v, __int_as_float(p));
}

// prev-lane value, lane 0 gets 0.0f (bound_ctrl: invalid lane -> 0)
__device__ __forceinline__ float dpp_shr1(float v) {
    int p = __builtin_amdgcn_update_dpp(0, __float_as_int(v),
                                        DPP_WAVE_SHR1, 0xF, 0xF, true);
    return __int_as_float(p);
}

// Fused producer/consumer CTC forward scan. One block per batch element n.
// 3 waves: wave 0 = consumer (serial recurrence, alpha in registers),
// waves 1,2 = producers (gather + exp emissions for the NEXT 32-step chunk
// into a double-buffered LDS ring). One __syncthreads per chunk.
// ALL cross-lane ops in the consumer are DPP (VALU path) -- no DS-unit
// latency on the serial chain. Math identical to the verified rounds 2-4.
__global__ __launch_bounds__(192) void ctc_scan(
    const float* __restrict__ lp,        // [T, N, C] fp32 log-softmax
    const int*   __restrict__ targets,   // [N, S]
    const int*   __restrict__ ilen,      // [N]
    const int*   __restrict__ tlen,      // [N]
    float*       __restrict__ v_out)     // [N] terminal log-alpha
{
    const int n    = blockIdx.x;
    const int tid  = threadIdx.x;
    const int wv   = tid >> 6;           // 0 = consumer, 1/2 = producers
    const int lane = tid & 63;

    __shared__ float s_pa[2][CH][64];    // exp(lp[t,n,tgA[lane]])
    __shared__ float s_pc[2][CH][64];    // exp(lp[t,n,tgB[lane]])
    __shared__ float s_pb[2][CH];        // exp(lp[t,n,0])

    const int tgA = targets[n * SS + 2 * lane];
    const int tgB = targets[n * SS + 2 * lane + 1];
    const float* lpn = lp + (size_t)n * CC;      // row t at lpn + t*NN*CC

    // ---------------- prologue: producers fill chunk 0 (t = 1..32) ----------
    if (wv != 0) {
        const int w = wv - 1;            // handles steps j = w, w+2, ..., w+30
        float va[16], vc[16];
#pragma unroll
        for (int i = 0; i < 16; ++i) {
            const int j = 2 * i + w;
            const float* row = lpn + (size_t)(1 + j) * (NN * CC);
            va[i] = row[tgA]; vc[i] = row[tgB];
        }
        float pbv = 0.f;
        if (w == 0 && lane < CH) pbv = lpn[(size_t)(1 + lane) * (NN * CC)];
#pragma unroll
        for (int i = 0; i < 16; ++i) {
            const int j = 2 * i + w;
            s_pa[0][j][lane] = __expf(va[i]);
            s_pc[0][j][lane] = __expf(vc[i]);
        }
        if (w == 0 && lane < CH) s_pb[0][lane] = __expf(pbv);
    }

    // consumer constants + t=0 init (reference: alpha0 zeros except s=0,1;
    // zeros in log domain == 1.0 linear)
    const int tgBm = (lane > 0) ? targets[n * SS + 2 * lane - 1] : -1;
    const float k1f = (lane > 0 && tgA != tgBm) ? 1.f : 0.f;
    const float k3f = (tgB != tgA) ? 1.f : 0.f;
    const int il    = ilen[n];
    const int vs    = 2 * tlen[n] - 1;   // odd, in [127, 255]
    const int vlane = vs >> 2;

    float a0 = 1.f, a1 = 1.f, a2 = 1.f, a3 = 1.f, ls = 0.f;
    if (wv == 0) {
        a0 = (lane == 0) ? __expf(lpn[0])   : 1.f;
        a1 = (lane == 0) ? __expf(lpn[tgA]) : 1.f;
    }
    float a3p = (lane == 0) ? 0.f : 1.f;
    float mr = 1.f, inv = 1.f;

    __syncthreads();

    // ---------------- main loop: 32 chunks of 32 steps ----------------------
    for (int cc = 0; cc < NCHUNK; ++cc) {
        const int b = cc & 1;
        if (wv == 0) {
            const int t0 = 1 + cc * CH;
            // 4-deep named-slot LDS prefetch (static indices after unroll)
            float qa[4], qc[4], qb[4];
#pragma unroll
            for (int k = 0; k < 4; ++k) {
                qa[k] = s_pa[b][k][lane];
                qc[k] = s_pc[b][k][lane];
                qb[k] = s_pb[b][k];
            }
#pragma unroll
            for (int j = 0; j < CH; ++j) {
                const int sl = j & 3;
                const float cpa = qa[sl], cpc = qc[sl], cpb = qb[sl];
                if (j + 4 < CH) {
                    qa[sl] = s_pa[b][j + 4][lane];
                    qc[sl] = s_pc[b][j + 4][lane];
                    qb[sl] = s_pb[b][j + 4];
                }

                float nb3 = fmaf(k3f, a1, a3 + a2) * cpc;
                float a3pn = dpp_shr1(nb3);               // VALU, ~4-8 cy
                float nb0 = (a0 + a3p) * cpb;
                float nb1 = fmaf(k1f, a3p, a0 + a1) * cpa;
                float nb2 = (a2 + a1) * cpb;

                // renorm every 8 steps: max of window-start values, DPP
                // butterfly spread one stage per step, applied at jj==7
                // (7 steps stale -- values only shrink; verified semantics)
                const int jj = j & 7;
                if      (jj == 0) mr = fmaxf(fmaxf(nb0, nb1), fmaxf(nb2, nb3));
                else if (jj == 1) mr = dpp_max_stage<DPP_QP_XOR1>(mr);
                else if (jj == 2) mr = dpp_max_stage<DPP_QP_XOR2>(mr);
                else if (jj == 3) mr = dpp_max_stage<DPP_HALF_MIRR>(mr);
                else if (jj == 4) mr = dpp_max_stage<DPP_ROW_MIRR>(mr);
                else if (jj == 5) mr = dpp_max_stage<DPP_BCAST15>(mr);
                else if (jj == 6) mr = dpp_max_stage<DPP_BCAST31>(mr);
                else { // jj == 7: lane 63 holds the wave max
                    const float mru = __int_as_float(
                        __builtin_amdgcn_readlane(__float_as_int(mr), 63));
                    inv = 1.0f / mru;
                    ls += __logf(mru);
                    nb0 *= inv; nb1 *= inv; nb2 *= inv; nb3 *= inv;
                }

                const int t = t0 + j;
                if (t == il - 1) {
                    if (lane == vlane) v_out[n] = __logf((vs & 2) ? nb3 : nb1) + ls;
                }

                a0 = nb0; a1 = nb1; a2 = nb2; a3 = nb3;
                if (jj == 7) a3pn *= inv;   // keep exchanged value consistent
                a3p = a3pn;
            }
            // t = 1024 (last step of last chunk) is garbage from a clamped
            // row but is never captured (il-1 <= 1023).
        } else if (cc + 1 < NCHUNK) {
            // producers fill chunk cc+1 into the other buffer
            const int w  = wv - 1;
            const int b2 = (cc + 1) & 1;
            const int t0 = 1 + (cc + 1) * CH;
            float va[16], vc[16];
#pragma unroll
            for (int i = 0; i < 16; ++i) {
                const int j = 2 * i + w;
                int t = t0 + j; if (t > TT - 1) t = TT - 1;   // clamp (tail)
                const float* row = lpn + (size_t)t * (NN * CC);
                va[i] = row[tgA]; vc[i] = row[tgB];
            }
            float pbv = 0.f;
            if (w == 0 && lane < CH) {
                int t = t0 + lane; if (t > TT - 1) t = TT - 1;
                pbv = lpn[(size_t)t * (NN * CC)];
            }
#pragma unroll
            for (int i = 0; i < 16; ++i) {
                const int j = 2 * i + w;
                s_pa[b2][j][lane] = __expf(va[i]);
                s_pc[b2][j][lane] = __expf(vc[i]);
            }
            if (w == 0 && lane < CH) s_pb[b2][lane] = __expf(pbv);
        }
        __syncthreads();
    }
}

// loss = -logsumexp(v) over the 64 batch elements; single wave
__global__ void ctc_reduce(const float* __restrict__ v, float* __restrict__ out)
{
    const int lane = threadIdx.x;
    float x = v[lane];
    float m = x;
#pragma unroll
    for (int off = 32; off > 0; off >>= 1) m = fmaxf(m, __shfl_xor(m, off));
    float e = __expf(x - m);
#pragma unroll
    for (int off = 32; off > 0; off >>= 1) e += __shfl_xor(e, off);
    if (lane == 0) out[0] = -(m + __logf(e));
}

extern "C" void kernel_launch(void* const* d_in, const int* in_sizes, int n_in,
                              void* d_out, int out_size, void* d_ws, size_t ws_size,
                              hipStream_t stream) {
    const float* lp      = (const float*)d_in[0];
    const int*   targets = (const int*)d_in[1];
    const int*   ilen    = (const int*)d_in[2];
    const int*   tlen    = (const int*)d_in[3];

    float* v   = (float*)d_ws;    // 64 floats of scratch
    float* out = (float*)d_out;

    ctc_scan<<<NN, 192, 0, stream>>>(lp, targets, ilen, tlen, v);
    ctc_reduce<<<1, 64, 0, stream>>>(v, out);
}

// Round 6
// 71.713 us; speedup vs baseline: 4.2351x; 1.1870x over previous
//
#include <hip/hip_runtime.h>
#include <math.h>

#define TT 1024
#define NN 64
#define CC 128
#define SS 128
#define CH 32          // steps per chunk
#define NCHUNK 32      // chunks covering t = 1..1024

// DPP controls (gfx9/CDNA encodings)
#define DPP_QP_XOR1   0xB1   // quad_perm [1,0,3,2]
#define DPP_QP_XOR2   0x4E   // quad_perm [2,3,0,1]
#define DPP_WAVE_SHR1 0x138  // whole-wave shift right by 1 lane
#define DPP_ROW_MIRR  0x140  // mirror within 16
#define DPP_HALF_MIRR 0x141  // mirror within 8
#define DPP_BCAST15   0x142  // lane15 -> next row
#define DPP_BCAST31   0x143  // lane31 -> upper half

template <int CTRL>
__device__ __forceinline__ float dpp_max_stage(float v) {
    int p = __builtin_amdgcn_update_dpp(__float_as_int(v), __float_as_int(v),
                                        CTRL, 0xF, 0xF, false);
    return fmaxf(v, __int_as_float(p));
}

// prev-lane value, lane 0 gets 0.0f (bound_ctrl: invalid lane -> 0)
__device__ __forceinline__ float dpp_shr1(float v) {
    int p = __builtin_amdgcn_update_dpp(0, __float_as_int(v),
                                        DPP_WAVE_SHR1, 0xF, 0xF, true);
    return __int_as_float(p);
}

// Fused producer/consumer CTC forward scan. One block per batch element n.
// 5 waves: wave 0 = consumer (serial recurrence, alpha in registers),
// waves 1-4 = producers (gather + exp next chunk's emissions into a
// double-buffered LDS ring). Emissions packed so the consumer reads
// 3 x ds_read_b128 per 4 steps (batched -> LDS latency amortized 4x):
//   s_e[buf][pair k][lane] = {pa(2k), pc(2k), pa(2k+1), pc(2k+1)}
//   s_pb4[buf][m]          = {pb(4m), pb(4m+1), pb(4m+2), pb(4m+3)} (uniform)
// Recurrence math identical to verified rounds 2-5 (absmax 0).
__global__ __launch_bounds__(320) void ctc_scan(
    const float* __restrict__ lp,        // [T, N, C] fp32 log-softmax
    const int*   __restrict__ targets,   // [N, S]
    const int*   __restrict__ ilen,      // [N]
    const int*   __restrict__ tlen,      // [N]
    float*       __restrict__ v_out)     // [N] terminal log-alpha
{
    const int n    = blockIdx.x;
    const int tid  = threadIdx.x;
    const int wv   = tid >> 6;           // 0 = consumer, 1..4 = producers
    const int lane = tid & 63;

    __shared__ float4 s_e[2][CH / 2][64];   // 32 KiB
    __shared__ float4 s_pb4[2][CH / 4];     // 256 B

    const int tgA = targets[n * SS + 2 * lane];
    const int tgB = targets[n * SS + 2 * lane + 1];
    const float* lpn = lp + (size_t)n * CC;      // row t at lpn + t*NN*CC

    // ---------------- prologue: producers fill chunk 0 (t = 1..32) ----------
    if (wv != 0) {
        const int w = wv - 1;            // pairs k = w, w+4, w+8, w+12
        float va[8], vc[8];
#pragma unroll
        for (int i = 0; i < 4; ++i) {
            const int k = w + 4 * i;
            const float* rowa = lpn + (size_t)(1 + 2 * k) * (NN * CC);
            const float* rowb = lpn + (size_t)(2 + 2 * k) * (NN * CC);
            va[2*i]   = rowa[tgA]; vc[2*i]   = rowa[tgB];
            va[2*i+1] = rowb[tgA]; vc[2*i+1] = rowb[tgB];
        }
        float pbv = 0.f;
        if (lane < 8) pbv = lpn[(size_t)(1 + w * 8 + lane) * (NN * CC)];
#pragma unroll
        for (int i = 0; i < 4; ++i) {
            const int k = w + 4 * i;
            s_e[0][k][lane] = make_float4(__expf(va[2*i]),   __expf(vc[2*i]),
                                          __expf(va[2*i+1]), __expf(vc[2*i+1]));
        }
        if (lane < 8) ((float*)s_pb4[0])[w * 8 + lane] = __expf(pbv);
    }

    // consumer constants + t=0 init (reference: alpha0 zeros except s=0,1;
    // zeros in log domain == 1.0 linear)
    const int tgBm = (lane > 0) ? targets[n * SS + 2 * lane - 1] : -1;
    const float k1f = (lane > 0 && tgA != tgBm) ? 1.f : 0.f;
    const float k3f = (tgB != tgA) ? 1.f : 0.f;
    const int il    = ilen[n];
    const int vs    = 2 * tlen[n] - 1;   // odd, in [127, 255]
    const int vlane = vs >> 2;

    float a0 = 1.f, a1 = 1.f, a2 = 1.f, a3 = 1.f, ls = 0.f;
    if (wv == 0) {
        a0 = (lane == 0) ? __expf(lpn[0])   : 1.f;
        a1 = (lane == 0) ? __expf(lpn[tgA]) : 1.f;
    }
    float a3p = (lane == 0) ? 0.f : 1.f;
    float mr = 1.f, inv = 1.f;

    __syncthreads();

    // ---------------- main loop: 32 chunks of 32 steps ----------------------
    for (int cc = 0; cc < NCHUNK; ++cc) {
        const int b = cc & 1;
        if (wv == 0) {
            const int t0 = 1 + cc * CH;
            // 2-batch (8-step) register lookahead; batch m = steps 4m..4m+3
            float4 eA0 = s_e[b][0][lane], eB0 = s_e[b][1][lane], pq0 = s_pb4[b][0];
            float4 eA1 = s_e[b][2][lane], eB1 = s_e[b][3][lane], pq1 = s_pb4[b][1];
#pragma unroll
            for (int m = 0; m < 8; ++m) {
                float4 ea, eb, pq;
                if (m & 1) { ea = eA1; eb = eB1; pq = pq1; }
                else       { ea = eA0; eb = eB0; pq = pq0; }
                if (m + 2 < 8) {
                    if (m & 1) { eA1 = s_e[b][2*(m+2)][lane]; eB1 = s_e[b][2*(m+2)+1][lane]; pq1 = s_pb4[b][m+2]; }
                    else       { eA0 = s_e[b][2*(m+2)][lane]; eB0 = s_e[b][2*(m+2)+1][lane]; pq0 = s_pb4[b][m+2]; }
                }
#pragma unroll
                for (int c = 0; c < 4; ++c) {
                    const int j   = 4 * m + c;
                    const float cpa = (c==0)?ea.x:(c==1)?ea.z:(c==2)?eb.x:eb.z;
                    const float cpc = (c==0)?ea.y:(c==1)?ea.w:(c==2)?eb.y:eb.w;
                    const float cpb = (c==0)?pq.x:(c==1)?pq.y:(c==2)?pq.z:pq.w;

                    float nb3 = fmaf(k3f, a1, a3 + a2) * cpc;
                    float a3pn = dpp_shr1(nb3);
                    float nb0 = (a0 + a3p) * cpb;
                    float nb1 = fmaf(k1f, a3p, a0 + a1) * cpa;
                    float nb2 = (a2 + a1) * cpb;

                    // renorm every 8 steps: DPP butterfly spread one stage
                    // per step, applied at jj==7 (stale-safe, values shrink)
                    const int jj = j & 7;
                    if      (jj == 0) mr = fmaxf(fmaxf(nb0, nb1), fmaxf(nb2, nb3));
                    else if (jj == 1) mr = dpp_max_stage<DPP_QP_XOR1>(mr);
                    else if (jj == 2) mr = dpp_max_stage<DPP_QP_XOR2>(mr);
                    else if (jj == 3) mr = dpp_max_stage<DPP_HALF_MIRR>(mr);
                    else if (jj == 4) mr = dpp_max_stage<DPP_ROW_MIRR>(mr);
                    else if (jj == 5) mr = dpp_max_stage<DPP_BCAST15>(mr);
                    else if (jj == 6) mr = dpp_max_stage<DPP_BCAST31>(mr);
                    else {
                        const float mru = __int_as_float(
                            __builtin_amdgcn_readlane(__float_as_int(mr), 63));
                        inv = 1.0f / mru;
                        ls += __logf(mru);
                        nb0 *= inv; nb1 *= inv; nb2 *= inv; nb3 *= inv;
                    }

                    const int t = t0 + j;
                    if (t == il - 1) {
                        if (lane == vlane) v_out[n] = __logf((vs & 2) ? nb3 : nb1) + ls;
                    }

                    a0 = nb0; a1 = nb1; a2 = nb2; a3 = nb3;
                    if (jj == 7) a3pn *= inv;
                    a3p = a3pn;
                }
            }
            // t = 1024 (last step of last chunk) is garbage from a clamped
            // row but is never captured (il-1 <= 1023).
        } else if (cc + 1 < NCHUNK) {
            // producers fill chunk cc+1 into the other buffer
            const int w  = wv - 1;
            const int b2 = (cc + 1) & 1;
            const int t0 = 1 + (cc + 1) * CH;
            float va[8], vc[8];
#pragma unroll
            for (int i = 0; i < 4; ++i) {
                const int k = w + 4 * i;
                int ta = t0 + 2 * k;     if (ta > TT - 1) ta = TT - 1;
                int tb = t0 + 2 * k + 1; if (tb > TT - 1) tb = TT - 1;
                const float* rowa = lpn + (size_t)ta * (NN * CC);
                const float* rowb = lpn + (size_t)tb * (NN * CC);
                va[2*i]   = rowa[tgA]; vc[2*i]   = rowa[tgB];
                va[2*i+1] = rowb[tgA]; vc[2*i+1] = rowb[tgB];
            }
            float pbv = 0.f;
            if (lane < 8) {
                int tp = t0 + w * 8 + lane; if (tp > TT - 1) tp = TT - 1;
                pbv = lpn[(size_t)tp * (NN * CC)];
            }
#pragma unroll
            for (int i = 0; i < 4; ++i) {
                const int k = w + 4 * i;
                s_e[b2][k][lane] = make_float4(__expf(va[2*i]),   __expf(vc[2*i]),
                                               __expf(va[2*i+1]), __expf(vc[2*i+1]));
            }
            if (lane < 8) ((float*)s_pb4[b2])[w * 8 + lane] = __expf(pbv);
        }
        __syncthreads();
    }
}

// loss = -logsumexp(v) over the 64 batch elements; single wave
__global__ void ctc_reduce(const float* __restrict__ v, float* __restrict__ out)
{
    const int lane = threadIdx.x;
    float x = v[lane];
    float m = x;
#pragma unroll
    for (int off = 32; off > 0; off >>= 1) m = fmaxf(m, __shfl_xor(m, off));
    float e = __expf(x - m);
#pragma unroll
    for (int off = 32; off > 0; off >>= 1) e += __shfl_xor(e, off);
    if (lane == 0) out[0] = -(m + __logf(e));
}

extern "C" void kernel_launch(void* const* d_in, const int* in_sizes, int n_in,
                              void* d_out, int out_size, void* d_ws, size_t ws_size,
                              hipStream_t stream) {
    const float* lp      = (const float*)d_in[0];
    const int*   targets = (const int*)d_in[1];
    const int*   ilen    = (const int*)d_in[2];
    const int*   tlen    = (const int*)d_in[3];

    float* v   = (float*)d_ws;    // 64 floats of scratch
    float* out = (float*)d_out;

    ctc_scan<<<NN, 320, 0, stream>>>(lp, targets, ilen, tlen, v);
    ctc_reduce<<<1, 64, 0, stream>>>(v, out);
}